// Round 6
// baseline (325.083 us; speedup 1.0000x reference)
//
#include <hip/hip_runtime.h>
#include <hip/hip_fp16.h>
#include <cmath>

// SVC_63737314673237 round 6: m97-style global_load_lds split-f16 MFMA GEMM.
// Math identical to verified R2-R4: dot = xh.sh + 2^-12*(xh.sl' + xl'.sh).
// R5 failed to compile: global_load_lds offset must be a literal constant.
// Fix: offset=0, kb folded into the source pointers (advance 32 f16/phase).
// Unswizzled [row][32f16] tiles (DMA = wave-uniform base + lane*16B),
// 24 x 1KB DMA chunks/phase (6 per wave), 46KB LDS -> 3 blocks/CU.

#define GAMMA 0.01f
constexpr int N  = 8192;
constexpr int D  = 256;
constexpr int S  = 5000;
constexpr int C  = 10;
constexpr int NV = 500;
constexpr int R  = 9;   // C-1

typedef _Float16 f16x8 __attribute__((ext_vector_type(8)));
typedef _Float16 f16x4 __attribute__((ext_vector_type(4)));
typedef float    f32x4 __attribute__((ext_vector_type(4)));
typedef const __attribute__((address_space(1))) void gas_t;
typedef __attribute__((address_space(3))) void las_t;

// ---------------- fused split + norms: one wave per row ---------------------
__global__ __launch_bounds__(256) void prep_kernel(const float* __restrict__ x,
                                                   const float* __restrict__ sv,
                                                   _Float16* __restrict__ xh,
                                                   _Float16* __restrict__ xl,
                                                   _Float16* __restrict__ sh,
                                                   _Float16* __restrict__ sl,
                                                   float* __restrict__ xn,
                                                   float* __restrict__ svn) {
    int gid  = blockIdx.x * blockDim.x + threadIdx.x;
    int wid  = gid >> 6;
    int lane = gid & 63;
    if (wid >= N + S) return;
    bool isx = wid < N;
    int  r   = isx ? wid : wid - N;
    const float* row = isx ? (x + (size_t)r * D) : (sv + (size_t)r * D);
    float4 v = reinterpret_cast<const float4*>(row)[lane];
    float s = v.x * v.x + v.y * v.y + v.z * v.z + v.w * v.w;
#pragma unroll
    for (int off = 32; off > 0; off >>= 1) s += __shfl_xor(s, off, 64);
    float vv[4] = {v.x, v.y, v.z, v.w};
    f16x4 h, l;
#pragma unroll
    for (int k = 0; k < 4; ++k) {
        _Float16 hi = (_Float16)vv[k];
        h[k] = hi;
        l[k] = (_Float16)((vv[k] - (float)hi) * 4096.0f);
    }
    size_t o = (size_t)r * D + lane * 4;
    *(f16x4*)((isx ? xh : sh) + o) = h;
    *(f16x4*)((isx ? xl : sl) + o) = l;
    if (lane == 0) (isx ? xn : svn)[r] = s;
}

// ---------------- DMA-staged split-MFMA GEMM + exp + weighted reduce --------
// grid (128 row tiles, 10 classes); 4 waves 2x2; wave tile 32x64 (2x4 of
// 16x16x32). ch outer (4 sv-chunks of 128), kb inner (8 x BK=32).
__global__ __launch_bounds__(256, 3) void svc_gemm(const _Float16* __restrict__ xh,
                                                   const _Float16* __restrict__ xl,
                                                   const _Float16* __restrict__ sh,
                                                   const _Float16* __restrict__ sl,
                                                   const float* __restrict__ a,
                                                   const float* __restrict__ xnorm,
                                                   const float* __restrict__ svnorm,
                                                   float* __restrict__ T) {
    __shared__ _Float16 As[2][64 * 32];    // [plane][row*32 + k]  (8 KB)
    __shared__ _Float16 Bs[2][128 * 32];   // [plane][row*32 + k]  (16 KB)
    __shared__ float a_sh[R][512];
    __shared__ float sn_sh[512];
    __shared__ float tred[64 * R];

    const int tid  = threadIdx.x;
    const int n0   = blockIdx.x * 64;
    const int cls  = blockIdx.y;
    const int w    = tid >> 6;
    const int lane = tid & 63;
    const int wm   = w >> 1;
    const int wn   = w & 1;
    const int lx   = lane & 15;
    const int quad = lane >> 4;

    for (int i = tid; i < R * 512; i += 256) {
        int r = i >> 9, cseg = i & 511;
        a_sh[r][cseg] = (cseg < NV) ? a[(size_t)r * S + cls * NV + cseg] : 0.0f;
    }
    for (int i = tid; i < 512; i += 256) {
        int svi = cls * NV + ((i < NV) ? i : NV - 1);
        sn_sh[i] = svnorm[svi];
    }
    for (int i = tid; i < 64 * R; i += 256) tred[i] = 0.0f;

    float xnr[2][4];
#pragma unroll
    for (int ti = 0; ti < 2; ++ti)
#pragma unroll
        for (int reg = 0; reg < 4; ++reg)
            xnr[ti][reg] = xnorm[n0 + wm * 32 + ti * 16 + quad * 4 + reg];

    float tloc[8][R];
#pragma unroll
    for (int i = 0; i < 8; ++i)
#pragma unroll
        for (int r = 0; r < R; ++r) tloc[i][r] = 0.0f;

    // frag read offsets (f16 units), unswizzled [row][k]
    int aoff[2], boff[4];
#pragma unroll
    for (int ti = 0; ti < 2; ++ti)
        aoff[ti] = (wm * 32 + ti * 16 + lx) * 32 + quad * 8;
#pragma unroll
    for (int tj = 0; tj < 4; ++tj)
        boff[tj] = (wn * 64 + tj * 16 + lx) * 32 + quad * 8;

    // ---- DMA chunk setup: wave w owns chunks q = 6w .. 6w+5 ----------------
    // q 0..7  -> A plane q>>2, rowchunk q&3   (16 rows x 32 f16 = 1 KB)
    // q 8..23 -> B plane (q-8)>>3, rowchunk (q-8)&7
    const int lrow = lane >> 2;            // 0..15 within chunk
    const int koff = (lane & 3) * 8;       // f16 offset within row
    const _Float16* gpA[6];
    const _Float16* bpl[6];
    int brseg[6];
    bool isA[6];
    las_t* ldst[6];
#pragma unroll
    for (int i = 0; i < 6; ++i) {
        int q = 6 * w + i;                 // wave-uniform
        if (q < 8) {
            isA[i] = true;
            int pl = q >> 2, rc = q & 3;
            const _Float16* src = pl ? xl : xh;
            gpA[i]  = src + (size_t)(n0 + rc * 16 + lrow) * D + koff;
            ldst[i] = (las_t*)&As[pl][rc * 512 + lrow * 32 + koff];
        } else {
            isA[i] = false;
            int t = q - 8, pl = t >> 3, rc = t & 7;
            bpl[i]   = pl ? sl : sh;
            brseg[i] = rc * 16 + lrow;
            gpA[i]   = nullptr;
            ldst[i]  = (las_t*)&Bs[pl][rc * 512 + lrow * 32 + koff];
        }
    }
    const int segend = cls * NV + NV - 1;

    f32x4 accM[2][4], accC[2][4];
#pragma unroll
    for (int ti = 0; ti < 2; ++ti)
#pragma unroll
        for (int tj = 0; tj < 4; ++tj) {
            accM[ti][tj] = (f32x4){0.f, 0.f, 0.f, 0.f};
            accC[ti][tj] = (f32x4){0.f, 0.f, 0.f, 0.f};
        }

    __syncthreads();

    for (int ch = 0; ch < 4; ++ch) {
        // per-ch source pointers; kb advances them by 32 f16 per phase
        const _Float16* gp[6];
#pragma unroll
        for (int i = 0; i < 6; ++i) {
            if (isA[i]) gp[i] = gpA[i];
            else {
                int svr = cls * NV + ch * 128 + brseg[i];
                if (svr > segend) svr = segend;
                gp[i] = bpl[i] + (size_t)svr * D + koff;
            }
        }
#pragma unroll
        for (int kb = 0; kb < 8; ++kb) {
#pragma unroll
            for (int i = 0; i < 6; ++i) {
                __builtin_amdgcn_global_load_lds((gas_t*)gp[i], ldst[i],
                                                 16, 0, 0);
                gp[i] += 32;               // next BK=32 slice
            }
            __syncthreads();               // drains vmcnt, tile visible

            f16x8 Ah[2], Al[2];
#pragma unroll
            for (int ti = 0; ti < 2; ++ti) {
                Ah[ti] = *(const f16x8*)(&As[0][aoff[ti]]);
                Al[ti] = *(const f16x8*)(&As[1][aoff[ti]]);
            }
#pragma unroll
            for (int tj = 0; tj < 4; ++tj) {
                f16x8 Bh = *(const f16x8*)(&Bs[0][boff[tj]]);
                f16x8 Bl = *(const f16x8*)(&Bs[1][boff[tj]]);
#pragma unroll
                for (int ti = 0; ti < 2; ++ti) {
                    accM[ti][tj] = __builtin_amdgcn_mfma_f32_16x16x32_f16(
                        Ah[ti], Bh, accM[ti][tj], 0, 0, 0);
                    accC[ti][tj] = __builtin_amdgcn_mfma_f32_16x16x32_f16(
                        Ah[ti], Bl, accC[ti][tj], 0, 0, 0);
                    accC[ti][tj] = __builtin_amdgcn_mfma_f32_16x16x32_f16(
                        Al[ti], Bh, accC[ti][tj], 0, 0, 0);
                }
            }
            __syncthreads();               // all reads done before next DMA
        }

        // chunk epilogue: exp + 9-way weighted accumulate (VALU)
#pragma unroll
        for (int tj = 0; tj < 4; ++tj) {
            int cseg = ch * 128 + wn * 64 + tj * 16 + lx;
            float sn = sn_sh[cseg];
            float av[R];
#pragma unroll
            for (int r = 0; r < R; ++r) av[r] = a_sh[r][cseg];
#pragma unroll
            for (int ti = 0; ti < 2; ++ti)
#pragma unroll
                for (int reg = 0; reg < 4; ++reg) {
                    float dot = accM[ti][tj][reg]
                              + accC[ti][tj][reg] * (1.0f / 4096.0f);
                    float e  = fmaf(2.0f * GAMMA, dot,
                                    -GAMMA * (xnr[ti][reg] + sn));
                    float kv = __expf(e);
#pragma unroll
                    for (int r = 0; r < R; ++r)
                        tloc[ti * 4 + reg][r] =
                            fmaf(av[r], kv, tloc[ti * 4 + reg][r]);
                }
        }
#pragma unroll
        for (int ti = 0; ti < 2; ++ti)
#pragma unroll
            for (int tj = 0; tj < 4; ++tj) {
                accM[ti][tj] = (f32x4){0.f, 0.f, 0.f, 0.f};
                accC[ti][tj] = (f32x4){0.f, 0.f, 0.f, 0.f};
            }
    }

    // butterfly-sum the 16 lanes sharing each row, then atomics from lx==0
#pragma unroll
    for (int i = 0; i < 8; ++i)
#pragma unroll
        for (int r = 0; r < R; ++r) {
            float v = tloc[i][r];
            v += __shfl_xor(v, 1, 64);
            v += __shfl_xor(v, 2, 64);
            v += __shfl_xor(v, 4, 64);
            v += __shfl_xor(v, 8, 64);
            tloc[i][r] = v;
        }
    if (lx == 0) {
#pragma unroll
        for (int i = 0; i < 8; ++i) {
            int ti = i >> 2, reg = i & 3;
            int row = wm * 32 + ti * 16 + quad * 4 + reg;
#pragma unroll
            for (int r = 0; r < R; ++r)
                atomicAdd(&tred[row * R + r], tloc[i][r]);
        }
    }
    __syncthreads();
    for (int i = tid; i < 64 * R; i += 256) {
        int row = i / R, r = i - row * R;
        T[(size_t)(n0 + row) * 90 + r * 10 + cls] = tred[i];
    }
}

// ---------------- pairwise voting + argmax ----------------------------------
__global__ __launch_bounds__(256) void vote_kernel(const float* __restrict__ T,
                                                   const float* __restrict__ b,
                                                   int* __restrict__ out) {
    int n = blockIdx.x * blockDim.x + threadIdx.x;
    if (n >= N) return;
    const float* Tn = T + (size_t)n * 90;
    float tv[90];
#pragma unroll
    for (int i = 0; i < 90; ++i) tv[i] = Tn[i];
    int counts[C];
#pragma unroll
    for (int k = 0; k < C; ++k) counts[k] = 0;
    int p = 0;
#pragma unroll
    for (int i = 0; i < C; ++i) {
#pragma unroll
        for (int j = i + 1; j < C; ++j) {
            float c = tv[i * 10 + j] + tv[(j - 1) * 10 + i] + b[p];
            if (c > 0.f) counts[i]++; else counts[j]++;
            ++p;
        }
    }
    int best = 0;
#pragma unroll
    for (int k = 1; k < C; ++k)
        if (counts[k] > counts[best]) best = k;
    out[n]     = best;
    out[N + n] = best;
}

extern "C" void kernel_launch(void* const* d_in, const int* in_sizes, int n_in,
                              void* d_out, int out_size, void* d_ws, size_t ws_size,
                              hipStream_t stream) {
    const float* x  = (const float*)d_in[0];   // [8192,256]
    const float* sv = (const float*)d_in[1];   // [5000,256]
    const float* a  = (const float*)d_in[2];   // [9,5000]
    const float* b  = (const float*)d_in[3];   // [45]
    int* out = (int*)d_out;

    char* wp = (char*)d_ws;
    _Float16* xh = (_Float16*)wp;  wp += (size_t)N * D * 2;
    _Float16* xl = (_Float16*)wp;  wp += (size_t)N * D * 2;
    _Float16* sh = (_Float16*)wp;  wp += (size_t)S * D * 2;
    _Float16* sl = (_Float16*)wp;  wp += (size_t)S * D * 2;
    float* xnorm  = (float*)wp;    wp += (size_t)N * 4;
    float* svnorm = (float*)wp;    wp += (size_t)S * 4;
    float* T      = (float*)wp;

    {   // fused split + norms
        int waves = N + S;
        prep_kernel<<<(waves * 64 + 255) / 256, 256, 0, stream>>>(
            x, sv, xh, xl, sh, sl, xnorm, svnorm);
    }
    {   // GEMM
        dim3 grid(N / 64, C);
        svc_gemm<<<grid, 256, 0, stream>>>(xh, xl, sh, sl, a, xnorm, svnorm, T);
    }
    {   // voting
        vote_kernel<<<N / 256, 256, 0, stream>>>(T, b, out);
    }
}

// Round 7
// 239.400 us; speedup vs baseline: 1.3579x; 1.3579x over previous
//
#include <hip/hip_runtime.h>
#include <cmath>

// SVC_63737314673237 round 7: bf16 2-plane merged-acc MFMA GEMM.
// x ~= bh + bl with bl = bf16(x - bh) UNSCALED (bf16 exponent = f32 -> exact
// range, no denormal risk). dot = bh.sh + bh.sl + bl.sh into ONE f32 acc:
// halves accumulator regs vs the f16 split, err ~1e-8 on decision values.
// R6 post-mortem: per-lane lds ptr broke global_load_lds (374MB phantom
// writes) -> DMA abandoned. R2-R6 all concurrency-starved (192 regs/wave ->
// 2 waves/SIMD). This round: regs ~165 (+launch_bounds(256,3)) and LDS 26KB
// (a/svnorm/xnorm from L2) -> 12 waves/CU.

#define GAMMA 0.01f
constexpr int N  = 8192;
constexpr int D  = 256;
constexpr int S  = 5000;
constexpr int C  = 10;
constexpr int NV = 500;
constexpr int R  = 9;   // C-1

typedef short s16x8 __attribute__((ext_vector_type(8)));  // 8 bf16
typedef short s16x4 __attribute__((ext_vector_type(4)));
typedef float f32x4 __attribute__((ext_vector_type(4)));

__device__ inline unsigned short bf16_rne(float f) {
    unsigned u = __float_as_uint(f);
    return (unsigned short)((u + 0x7FFFu + ((u >> 16) & 1u)) >> 16);
}

// ---------------- split into 2 bf16 planes + norms: one wave per row --------
__global__ __launch_bounds__(256) void prep_kernel(const float* __restrict__ x,
                                                   const float* __restrict__ sv,
                                                   unsigned short* __restrict__ xbh,
                                                   unsigned short* __restrict__ xbl,
                                                   unsigned short* __restrict__ sbh,
                                                   unsigned short* __restrict__ sbl,
                                                   float* __restrict__ xn,
                                                   float* __restrict__ svn) {
    int gid  = blockIdx.x * blockDim.x + threadIdx.x;
    int wid  = gid >> 6;
    int lane = gid & 63;
    if (wid >= N + S) return;
    bool isx = wid < N;
    int  r   = isx ? wid : wid - N;
    const float* row = isx ? (x + (size_t)r * D) : (sv + (size_t)r * D);
    float4 v = reinterpret_cast<const float4*>(row)[lane];
    float s = v.x * v.x + v.y * v.y + v.z * v.z + v.w * v.w;
#pragma unroll
    for (int off = 32; off > 0; off >>= 1) s += __shfl_xor(s, off, 64);
    float vv[4] = {v.x, v.y, v.z, v.w};
    s16x4 h, l;
#pragma unroll
    for (int k = 0; k < 4; ++k) {
        unsigned short hb = bf16_rne(vv[k]);
        float hf = __uint_as_float((unsigned)hb << 16);
        h[k] = (short)hb;
        l[k] = (short)bf16_rne(vv[k] - hf);
    }
    size_t o = (size_t)r * D + lane * 4;
    *(s16x4*)((isx ? xbh : sbh) + o) = h;
    *(s16x4*)((isx ? xbl : sbl) + o) = l;
    if (lane == 0) (isx ? xn : svn)[r] = s;
}

// ---------------- bf16 2-plane MFMA GEMM + exp + weighted reduce ------------
// grid (128 row tiles, 10 classes); 4 waves 2x2; wave tile 32x64 = 2x4 tiles
// of mfma_f32_16x16x32_bf16, 3 MFMAs/tile (hh,hl,lh) into ONE acc.
// 4 chunks x 8 kb phases; single-buffer LDS, plain [row][32] layout.
__global__ __launch_bounds__(256, 3) void svc_gemm(
        const unsigned short* __restrict__ xbh,
        const unsigned short* __restrict__ xbl,
        const unsigned short* __restrict__ sbh,
        const unsigned short* __restrict__ sbl,
        const float* __restrict__ a,
        const float* __restrict__ xnorm,
        const float* __restrict__ svnorm,
        float* __restrict__ T) {
    __shared__ short As[2][64 * 32];      // [plane][row*32+k]  8 KB
    __shared__ short Bs[2][128 * 32];     // [plane][row*32+k] 16 KB
    __shared__ float tred[64 * R];        // 2.25 KB

    const int tid  = threadIdx.x;
    const int n0   = blockIdx.x * 64;
    const int cls  = blockIdx.y;
    const int w    = tid >> 6;
    const int lane = tid & 63;
    const int wm   = w >> 1;
    const int wn   = w & 1;
    const int lx   = lane & 15;
    const int quad = lane >> 4;

    for (int i = tid; i < 64 * R; i += 256) tred[i] = 0.0f;

    float tloc[8][R];
#pragma unroll
    for (int i = 0; i < 8; ++i)
#pragma unroll
        for (int r = 0; r < R; ++r) tloc[i][r] = 0.0f;

    // frag read offsets (bf16 units), plain [row][32]
    int aoff[2], boff[4];
#pragma unroll
    for (int ti = 0; ti < 2; ++ti)
        aoff[ti] = (wm * 32 + ti * 16 + lx) * 32 + quad * 8;
#pragma unroll
    for (int tj = 0; tj < 4; ++tj)
        boff[tj] = (wn * 64 + tj * 16 + lx) * 32 + quad * 8;

    // staging maps: A row=tid>>2 (64 rows), B rows tid>>2 and 64+(tid>>2)
    const int srow = tid >> 2, sks = tid & 3;
    const int adst  = srow * 32 + sks * 8;
    const int bdst0 = srow * 32 + sks * 8;
    const int bdst1 = (64 + srow) * 32 + sks * 8;
    const size_t abase = (size_t)(n0 + srow) * D + sks * 8;
    const int segend = cls * NV + NV - 1;

    f32x4 acc[2][4];
#pragma unroll
    for (int ti = 0; ti < 2; ++ti)
#pragma unroll
        for (int tj = 0; tj < 4; ++tj) acc[ti][tj] = (f32x4){0.f, 0.f, 0.f, 0.f};

    __syncthreads();

    for (int ch = 0; ch < 4; ++ch) {
        int svr0 = cls * NV + ch * 128 + srow;       if (svr0 > segend) svr0 = segend;
        int svr1 = cls * NV + ch * 128 + 64 + srow;  if (svr1 > segend) svr1 = segend;
        const size_t b0 = (size_t)svr0 * D + sks * 8;
        const size_t b1 = (size_t)svr1 * D + sks * 8;

        for (int kb = 0; kb < 8; ++kb) {
            const int ko = kb * 32;
            s16x8 vAh = *(const s16x8*)(xbh + abase + ko);
            s16x8 vAl = *(const s16x8*)(xbl + abase + ko);
            s16x8 vB0h = *(const s16x8*)(sbh + b0 + ko);
            s16x8 vB0l = *(const s16x8*)(sbl + b0 + ko);
            s16x8 vB1h = *(const s16x8*)(sbh + b1 + ko);
            s16x8 vB1l = *(const s16x8*)(sbl + b1 + ko);
            *(s16x8*)(&As[0][adst])  = vAh;
            *(s16x8*)(&As[1][adst])  = vAl;
            *(s16x8*)(&Bs[0][bdst0]) = vB0h;
            *(s16x8*)(&Bs[1][bdst0]) = vB0l;
            *(s16x8*)(&Bs[0][bdst1]) = vB1h;
            *(s16x8*)(&Bs[1][bdst1]) = vB1l;
            __syncthreads();

            s16x8 Ah[2], Al[2];
#pragma unroll
            for (int ti = 0; ti < 2; ++ti) {
                Ah[ti] = *(const s16x8*)(&As[0][aoff[ti]]);
                Al[ti] = *(const s16x8*)(&As[1][aoff[ti]]);
            }
#pragma unroll
            for (int tj = 0; tj < 4; ++tj) {
                s16x8 Bh = *(const s16x8*)(&Bs[0][boff[tj]]);
                s16x8 Bl = *(const s16x8*)(&Bs[1][boff[tj]]);
#pragma unroll
                for (int ti = 0; ti < 2; ++ti) {
                    acc[ti][tj] = __builtin_amdgcn_mfma_f32_16x16x32_bf16(
                        Ah[ti], Bh, acc[ti][tj], 0, 0, 0);
                    acc[ti][tj] = __builtin_amdgcn_mfma_f32_16x16x32_bf16(
                        Ah[ti], Bl, acc[ti][tj], 0, 0, 0);
                    acc[ti][tj] = __builtin_amdgcn_mfma_f32_16x16x32_bf16(
                        Al[ti], Bh, acc[ti][tj], 0, 0, 0);
                }
            }
            __syncthreads();
        }

        // chunk epilogue: exp + 9-way weighted accumulate (a, norms from L2)
        float xnv[2][4];
#pragma unroll
        for (int ti = 0; ti < 2; ++ti)
#pragma unroll
            for (int reg = 0; reg < 4; ++reg)
                xnv[ti][reg] = xnorm[n0 + wm * 32 + ti * 16 + quad * 4 + reg];
#pragma unroll
        for (int tj = 0; tj < 4; ++tj) {
            int cseg = ch * 128 + wn * 64 + tj * 16 + lx;
            bool ok = cseg < NV;
            int ci  = ok ? cseg : NV - 1;
            float sn = svnorm[cls * NV + ci];
            float av[R];
#pragma unroll
            for (int r = 0; r < R; ++r)
                av[r] = ok ? a[(size_t)r * S + cls * NV + cseg] : 0.0f;
#pragma unroll
            for (int ti = 0; ti < 2; ++ti)
#pragma unroll
                for (int reg = 0; reg < 4; ++reg) {
                    float e  = fmaf(2.0f * GAMMA, acc[ti][tj][reg],
                                    -GAMMA * (xnv[ti][reg] + sn));
                    float kv = __expf(e);
#pragma unroll
                    for (int r = 0; r < R; ++r)
                        tloc[ti * 4 + reg][r] =
                            fmaf(av[r], kv, tloc[ti * 4 + reg][r]);
                }
        }
#pragma unroll
        for (int ti = 0; ti < 2; ++ti)
#pragma unroll
            for (int tj = 0; tj < 4; ++tj)
                acc[ti][tj] = (f32x4){0.f, 0.f, 0.f, 0.f};
    }

    // butterfly-sum the 16 lanes sharing each row, then atomics from lx==0
#pragma unroll
    for (int i = 0; i < 8; ++i)
#pragma unroll
        for (int r = 0; r < R; ++r) {
            float v = tloc[i][r];
            v += __shfl_xor(v, 1, 64);
            v += __shfl_xor(v, 2, 64);
            v += __shfl_xor(v, 4, 64);
            v += __shfl_xor(v, 8, 64);
            tloc[i][r] = v;
        }
    if (lx == 0) {
#pragma unroll
        for (int i = 0; i < 8; ++i) {
            int ti = i >> 2, reg = i & 3;
            int row = wm * 32 + ti * 16 + quad * 4 + reg;
#pragma unroll
            for (int r = 0; r < R; ++r)
                atomicAdd(&tred[row * R + r], tloc[i][r]);
        }
    }
    __syncthreads();
    for (int i = tid; i < 64 * R; i += 256) {
        int row = i / R, r = i - row * R;
        T[(size_t)(n0 + row) * 90 + r * 10 + cls] = tred[i];
    }
}

// ---------------- pairwise voting + argmax ----------------------------------
__global__ __launch_bounds__(256) void vote_kernel(const float* __restrict__ T,
                                                   const float* __restrict__ b,
                                                   int* __restrict__ out) {
    int n = blockIdx.x * blockDim.x + threadIdx.x;
    if (n >= N) return;
    const float* Tn = T + (size_t)n * 90;
    float tv[90];
#pragma unroll
    for (int i = 0; i < 90; ++i) tv[i] = Tn[i];
    int counts[C];
#pragma unroll
    for (int k = 0; k < C; ++k) counts[k] = 0;
    int p = 0;
#pragma unroll
    for (int i = 0; i < C; ++i) {
#pragma unroll
        for (int j = i + 1; j < C; ++j) {
            float c = tv[i * 10 + j] + tv[(j - 1) * 10 + i] + b[p];
            if (c > 0.f) counts[i]++; else counts[j]++;
            ++p;
        }
    }
    int best = 0;
#pragma unroll
    for (int k = 1; k < C; ++k)
        if (counts[k] > counts[best]) best = k;
    out[n]     = best;
    out[N + n] = best;
}

extern "C" void kernel_launch(void* const* d_in, const int* in_sizes, int n_in,
                              void* d_out, int out_size, void* d_ws, size_t ws_size,
                              hipStream_t stream) {
    const float* x  = (const float*)d_in[0];   // [8192,256]
    const float* sv = (const float*)d_in[1];   // [5000,256]
    const float* a  = (const float*)d_in[2];   // [9,5000]
    const float* b  = (const float*)d_in[3];   // [45]
    int* out = (int*)d_out;

    char* wp = (char*)d_ws;
    unsigned short* xbh = (unsigned short*)wp;  wp += (size_t)N * D * 2;
    unsigned short* xbl = (unsigned short*)wp;  wp += (size_t)N * D * 2;
    unsigned short* sbh = (unsigned short*)wp;  wp += (size_t)S * D * 2;
    unsigned short* sbl = (unsigned short*)wp;  wp += (size_t)S * D * 2;
    float* xnorm  = (float*)wp;                 wp += (size_t)N * 4;
    float* svnorm = (float*)wp;                 wp += (size_t)S * 4;
    float* T      = (float*)wp;

    {   // split + norms
        int waves = N + S;
        prep_kernel<<<(waves * 64 + 255) / 256, 256, 0, stream>>>(
            x, sv, xbh, xbl, sbh, sbl, xnorm, svnorm);
    }
    {   // GEMM
        dim3 grid(N / 64, C);
        svc_gemm<<<grid, 256, 0, stream>>>(xbh, xbl, sbh, sbl, a, xnorm, svnorm, T);
    }
    {   // voting
        vote_kernel<<<N / 256, 256, 0, stream>>>(T, b, out);
    }
}